// Round 9
// baseline (117.448 us; speedup 1.0000x reference)
//
#include <hip/hip_runtime.h>

#define NBATCH 4096
#define OUT2 (NBATCH * 64)

typedef _Float16 f16;
typedef __attribute__((ext_vector_type(8))) _Float16 f16x8;
typedef __attribute__((ext_vector_type(4))) float f32x4;

__device__ __forceinline__ float lrelu(float x) { return fmaxf(x, 0.2f * x); }
__device__ __forceinline__ float elu1(float x)  { return x > 0.0f ? x : __expf(x) - 1.0f; }
__device__ __forceinline__ void lds_fence() {
    asm volatile("s_waitcnt lgkmcnt(0)" ::: "memory");
}
// pack two f32 -> f16 (RNE, same as scalar casts) into one dword, low = a
__device__ __forceinline__ unsigned pk2(float a, float b) {
    union { f16 h[2]; unsigned u; } t;
    t.h[0] = (f16)a; t.h[1] = (f16)b;
    return t.u;
}
union F16x8U { unsigned u[4]; f16x8 v; };

// 4-lane-group transpose: MFMA D-layout tile pair {t0,t1} -> A/B-frag.
// Target lane (c,q) elem j takes reg r=j&3 of tile (q>>1) from source lane
// (c, 2(q&1)+(j>>2)); s0 = c+32*(q&1), s1 = s0+16. Tile select AFTER the
// shuffle, in the destination lane (R6 bug).
__device__ __forceinline__ f16x8 xpose(unsigned p0l, unsigned p0h,
                                       unsigned p1l, unsigned p1h,
                                       int s0, int s1, bool hiSel) {
    const unsigned a0l = (unsigned)__shfl((int)p0l, s0, 64);
    const unsigned a0h = (unsigned)__shfl((int)p0h, s0, 64);
    const unsigned b0l = (unsigned)__shfl((int)p0l, s1, 64);
    const unsigned b0h = (unsigned)__shfl((int)p0h, s1, 64);
    const unsigned a1l = (unsigned)__shfl((int)p1l, s0, 64);
    const unsigned a1h = (unsigned)__shfl((int)p1h, s0, 64);
    const unsigned b1l = (unsigned)__shfl((int)p1l, s1, 64);
    const unsigned b1h = (unsigned)__shfl((int)p1h, s1, 64);
    F16x8U o;
    o.u[0] = hiSel ? a1l : a0l;
    o.u[1] = hiSel ? a1h : a0h;
    o.u[2] = hiSel ? b1l : b0l;
    o.u[3] = hiSel ? b1h : b0h;
    return o.v;
}

// ---------------- prep ----------------
// ws: [0,32768)      w2b  f16 MFMA B-frags: w2b[((F2T*4+kf)*64+ln)*8+j] = W2[kf*32+(ln>>4)*8+j][F2T*16+(ln&15)]
//     [32768,32792)  w1a  f32[6] = {W1^T@a1[:128] (3), W1^T@a1[128:] (3)}
//     [32800,36896)  w2ab f16 B-frags of [W2@a2[:128] | W2@a2[128:]] (2 cols)
__global__ void prep(const float* __restrict__ W2, const float* __restrict__ W1,
                     const float* __restrict__ a1, const float* __restrict__ a2,
                     f16* __restrict__ w2b, float* __restrict__ w1a, f16* __restrict__ w2ab) {
    const int flat = blockIdx.x * 256 + threadIdx.x;   // 0..16383
    const int slot = flat >> 3, j = flat & 7;
    const int F2T = slot >> 8, kf = (slot >> 6) & 3, ln = slot & 63;
    const int lq = ln >> 4, lr = ln & 15;
    w2b[flat] = (f16)W2[(kf * 32 + lq * 8 + j) * 128 + F2T * 16 + lr];
    if (flat < 2048) {
        const int ks = flat >> 9, ln2 = (flat >> 3) & 63, jj = flat & 7;
        const int k = ks * 32 + ((ln2 >> 4) & 3) * 8 + jj;
        const int n = ln2 & 15;
        float v = 0.f;
        if (n < 2) {
            const float* av = a2 + n * 128;
            for (int f2 = 0; f2 < 128; ++f2) v = fmaf(W2[k * 128 + f2], av[f2], v);
        }
        w2ab[flat] = (f16)v;
    }
    if (flat >= 16381) {   // last 3 threads: w1a
        const int c = flat - 16381;
        float si = 0.f, sj = 0.f;
        for (int f = 0; f < 128; ++f) {
            const float w = W1[c * 128 + f];
            si = fmaf(w, a1[f], si);
            sj = fmaf(w, a1[128 + f], sj);
        }
        w1a[c] = si; w1a[3 + c] = sj;
    }
}

// FOUR independent batch-waves per 256-thread block; LDS-free compute core.
// R0-R8 synthesis: batch throughput/CU is invariant (~16 per 46us) across all
// arrangements with every pipe <50% busy; per-wave stall mass (~35k cyc) is
// unexplained by chain latency unless DS-pipe ops (~330/batch, also invariant)
// see inflated latency from PHASE-ALIGNED QUEUEING: identical programs, waves
// start together, bursts collide on the single per-CU LDS/crossbar pipe.
// This round: (1) staggered wave starts (s_sleep ramp) to de-convoy — the
// falsification test; (2) pk2-packed softmax frag construction (VALU diet);
// (3) explicit distance-1 bw2 prefetch (hides L2 latency; R8 showed the
// compiler won't do it itself).
// (256,2): VGPR cap 256 — R1 showed forcing a low cap spills catastrophically.
__global__ __launch_bounds__(256, 2)
void gat_kernel(const float* __restrict__ users,
                const float* __restrict__ W1,
                const f16* __restrict__ w2b,
                const float* __restrict__ w1a,
                const f16* __restrict__ w2ab,
                const float* __restrict__ mw1,
                const float* __restrict__ mb1,
                const float* __restrict__ mw2,
                const float* __restrict__ mb2,
                float* __restrict__ out)
{
    const int wid  = threadIdx.x >> 6;            // wave in block = batch slot
    const int b    = blockIdx.x * 4 + wid;
    const int lane = threadIdx.x & 63;
    const int lr   = lane & 15;
    const int lq   = lane >> 4;
    const int s0   = (lane & 15) | ((lane & 16) << 1);   // c + 32*(q&1)
    const int s1   = s0 + 16;
    const bool hiSel = (lane & 32) != 0;                 // q>>1

    // ---- de-convoy stagger: 0..15 units of ~1k cycles, wave-uniform ----
    {
        const int stg = __builtin_amdgcn_readfirstlane(((blockIdx.x >> 3) & 3) * 4 + wid);
        for (int i = 0; i < stg; ++i) __builtin_amdgcn_s_sleep(16);
    }

    __shared__ __align__(16) char smem[4 * 1280];
    char*  sw    = smem + wid * 1280;             // wave-private slice
    float* sSi   = (float*)(sw);                  // [64]
    float* sSj   = (float*)(sw + 256);            // [64]
    float* sPool = (float*)(sw + 512);            // [128]
    float* sHid  = (float*)(sw + 1024);           // [32]

    const float* u = users + b * 192;

    // ---- scores layer 1: rank-3 exact fp32 ----
    {
        const float x = u[lane * 3], y = u[lane * 3 + 1], z = u[lane * 3 + 2];
        sSi[lane] = fmaf(x, w1a[0], fmaf(y, w1a[1], z * w1a[2]));
        sSj[lane] = fmaf(x, w1a[3], fmaf(y, w1a[4], z * w1a[5]));
    }
    lds_fence();

    // ---- softmax-1 (inv folded into frags, pk2-packed) + product-1 ----
    f16x8 bfr[4];        // normalized PU^T as B-frags (16 VGPRs)
    {
        float sjv[16];
        *(float4*)&sjv[0]  = *(const float4*)&sSj[lq * 8];
        *(float4*)&sjv[4]  = *(const float4*)&sSj[lq * 8 + 4];
        *(float4*)&sjv[8]  = *(const float4*)&sSj[32 + lq * 8];
        *(float4*)&sjv[12] = *(const float4*)&sSj[32 + lq * 8 + 4];
        f16x8 ap[4][2];
        #pragma unroll
        for (int mt = 0; mt < 4; ++mt) {
            const float si = sSi[mt * 16 + lr];
            float pv[16];
            float lsum = 0.f;
            #pragma unroll
            for (int jj = 0; jj < 8; ++jj) {
                const float p0 = __expf(lrelu(si + sjv[jj]));
                const float p1 = __expf(lrelu(si + sjv[8 + jj]));
                pv[jj] = p0; pv[8 + jj] = p1;
                lsum += p0 + p1;
            }
            lsum += __shfl_xor(lsum, 16, 64);
            lsum += __shfl_xor(lsum, 32, 64);
            const float inv = 1.0f / lsum;
            F16x8U a0, a1;
            #pragma unroll
            for (int d = 0; d < 4; ++d) {
                a0.u[d] = pk2(pv[2 * d] * inv,     pv[2 * d + 1] * inv);
                a1.u[d] = pk2(pv[8 + 2 * d] * inv, pv[8 + 2 * d + 1] * inv);
            }
            ap[mt][0] = a0.v;
            ap[mt][1] = a1.v;
        }
        // product-1: PU^T = U^T @ P1n^T  (P already normalized)
        f16x8 af2[2];
        #pragma unroll
        for (int ks = 0; ks < 2; ++ks) {
            #pragma unroll
            for (int jj = 0; jj < 8; ++jj) {
                const int node = ks * 32 + lq * 8 + jj;
                af2[ks][jj] = (lr < 3) ? (f16)u[node * 3 + lr] : (f16)0.f;
            }
        }
        #pragma unroll
        for (int nt = 0; nt < 4; ++nt) {
            f32x4 d1 = (f32x4){0.f, 0.f, 0.f, 0.f};
            d1 = __builtin_amdgcn_mfma_f32_16x16x32_f16(af2[0], ap[nt][0], d1, 0, 0, 0);
            d1 = __builtin_amdgcn_mfma_f32_16x16x32_f16(af2[1], ap[nt][1], d1, 0, 0, 0);
            const float c0 = __shfl(d1[0], lr, 64);
            const float c1 = __shfl(d1[1], lr, 64);
            const float c2 = __shfl(d1[2], lr, 64);
            F16x8U t;
            t.u[0] = (lq == 0) ? pk2(c0, c1)   : 0u;
            t.u[1] = (lq == 0) ? pk2(c2, 0.0f) : 0u;
            t.u[2] = 0u; t.u[3] = 0u;
            bfr[nt] = t.v;
        }
    }

    // ===== layer-1: h1^T = W1^T @ PUn^T, in-register transpose to A-frags =====
    f16x8 hf[4][4];      // 64 VGPRs: h1 A-frags
    #pragma unroll
    for (int h = 0; h < 2; ++h) {
        #pragma unroll
        for (int ksl = 0; ksl < 2; ++ksl) {
            f32x4 acc[4][2];
            #pragma unroll
            for (int tp = 0; tp < 2; ++tp) {
                const int ftl = 2 * ksl + tp;
                f16x8 af3;      // W1^T A-frag
                #pragma unroll
                for (int jj = 0; jj < 8; ++jj) af3[jj] = (f16)0.f;
                if (lq == 0) {
                    #pragma unroll
                    for (int jj = 0; jj < 3; ++jj)
                        af3[jj] = (f16)W1[jj * 128 + (h * 4 + ftl) * 16 + lr];
                }
                #pragma unroll
                for (int nt = 0; nt < 4; ++nt) {
                    acc[nt][tp] = (f32x4){0.f, 0.f, 0.f, 0.f};
                    acc[nt][tp] = __builtin_amdgcn_mfma_f32_16x16x32_f16(af3, bfr[nt], acc[nt][tp], 0, 0, 0);
                }
            }
            #pragma unroll
            for (int nt = 0; nt < 4; ++nt) {
                const unsigned p0l = pk2(elu1(acc[nt][0][0]), elu1(acc[nt][0][1]));
                const unsigned p0h = pk2(elu1(acc[nt][0][2]), elu1(acc[nt][0][3]));
                const unsigned p1l = pk2(elu1(acc[nt][1][0]), elu1(acc[nt][1][1]));
                const unsigned p1h = pk2(elu1(acc[nt][1][2]), elu1(acc[nt][1][3]));
                hf[nt][h * 2 + ksl] = xpose(p0l, p0h, p1l, p1h, s0, s1, hiSel);
            }
        }
    }

    // ---- scores layer 2 via MFMA ----
    {
        f32x4 sacc[4];
        #pragma unroll
        for (int mt = 0; mt < 4; ++mt) sacc[mt] = (f32x4){0.f, 0.f, 0.f, 0.f};
        #pragma unroll
        for (int ks = 0; ks < 4; ++ks) {
            f16x8 bsw = *(const f16x8*)(w2ab + (ks * 64 + lane) * 8);
            #pragma unroll
            for (int mt = 0; mt < 4; ++mt)
                sacc[mt] = __builtin_amdgcn_mfma_f32_16x16x32_f16(hf[mt][ks], bsw, sacc[mt], 0, 0, 0);
        }
        lds_fence();   // softmax-1's sSi/sSj reads ordered before overwrite
        if (lr < 2) {
            float* dst = (lr == 0) ? sSi : sSj;
            #pragma unroll
            for (int mt = 0; mt < 4; ++mt)
                #pragma unroll
                for (int r = 0; r < 4; ++r)
                    dst[mt * 16 + lq * 4 + r] = sacc[mt][r];
        }
    }
    lds_fence();

    // ---- softmax-2 built once (inv2 folded into bp, pk2-packed) ----
    f16x8 bp[4][2];      // 32 VGPRs
    {
        float sjv[16];
        *(float4*)&sjv[0]  = *(const float4*)&sSj[lq * 8];
        *(float4*)&sjv[4]  = *(const float4*)&sSj[lq * 8 + 4];
        *(float4*)&sjv[8]  = *(const float4*)&sSj[32 + lq * 8];
        *(float4*)&sjv[12] = *(const float4*)&sSj[32 + lq * 8 + 4];
        #pragma unroll
        for (int mt = 0; mt < 4; ++mt) {
            const float si = sSi[mt * 16 + lr];
            float pv[16];
            float lsum = 0.f;
            #pragma unroll
            for (int jj = 0; jj < 8; ++jj) {
                const float p0 = __expf(lrelu(si + sjv[jj]));
                const float p1 = __expf(lrelu(si + sjv[8 + jj]));
                pv[jj] = p0; pv[8 + jj] = p1;
                lsum += p0 + p1;
            }
            lsum += __shfl_xor(lsum, 16, 64);
            lsum += __shfl_xor(lsum, 32, 64);
            const float inv = 1.0f / lsum;
            F16x8U b0, b1;
            #pragma unroll
            for (int d = 0; d < 4; ++d) {
                b0.u[d] = pk2(pv[2 * d] * inv,     pv[2 * d + 1] * inv);
                b1.u[d] = pk2(pv[8 + 2 * d] * inv, pv[8 + 2 * d + 1] * inv);
            }
            bp[mt][0] = b0.v;
            bp[mt][1] = b1.v;
        }
    }

    // ======= fused F + E1, in-register, distance-1 bw2 prefetch =======
    {
        f16x8 bw2c[4];
        #pragma unroll
        for (int kf = 0; kf < 4; ++kf)
            bw2c[kf] = *(const f16x8*)(w2b + ((0 * 4 + kf) * 64 + lane) * 8);

        #pragma unroll 1
        for (int ft = 0; ft < 8; ++ft) {
            f16x8 bw2n[4];
            if (ft < 7) {     // issue next tile's loads before current compute
                #pragma unroll
                for (int kf = 0; kf < 4; ++kf)
                    bw2n[kf] = *(const f16x8*)(w2b + (((ft + 1) * 4 + kf) * 64 + lane) * 8);
            }

            unsigned pkq[4][2];
            #pragma unroll
            for (int nt = 0; nt < 4; ++nt) {
                f32x4 acc = (f32x4){0.f, 0.f, 0.f, 0.f};
                #pragma unroll
                for (int kf = 0; kf < 4; ++kf)
                    acc = __builtin_amdgcn_mfma_f32_16x16x32_f16(hf[nt][kf], bw2c[kf], acc, 0, 0, 0);
                pkq[nt][0] = pk2(acc[0], acc[1]);
                pkq[nt][1] = pk2(acc[2], acc[3]);
            }
            const f16x8 bh0 = xpose(pkq[0][0], pkq[0][1], pkq[1][0], pkq[1][1], s0, s1, hiSel);
            const f16x8 bh1 = xpose(pkq[2][0], pkq[2][1], pkq[3][0], pkq[3][1], s0, s1, hiSel);

            float mx = -1e30f;
            #pragma unroll
            for (int mt = 0; mt < 4; ++mt) {
                f32x4 acc = (f32x4){0.f, 0.f, 0.f, 0.f};
                acc = __builtin_amdgcn_mfma_f32_16x16x32_f16(bp[mt][0], bh0, acc, 0, 0, 0);
                acc = __builtin_amdgcn_mfma_f32_16x16x32_f16(bp[mt][1], bh1, acc, 0, 0, 0);
                mx = fmaxf(mx, fmaxf(fmaxf(acc[0], acc[1]), fmaxf(acc[2], acc[3])));
            }
            mx = fmaxf(mx, __shfl_xor(mx, 16, 64));
            mx = fmaxf(mx, __shfl_xor(mx, 32, 64));
            if (lane < 16) sPool[ft * 16 + lane] = elu1(mx);

            if (ft < 7) {
                #pragma unroll
                for (int kf = 0; kf < 4; ++kf) bw2c[kf] = bw2n[kf];
            }
        }
    }
    lds_fence();

    // ================= Readout =================
    {
        const int o = lane & 31, hh = lane >> 5;
        float s0r = 0.f;
        #pragma unroll 8
        for (int kk = 0; kk < 64; ++kk) {
            const int c = hh * 64 + kk;
            s0r = fmaf(sPool[c], mw1[c * 32 + o], s0r);
        }
        s0r += __shfl_xor(s0r, 32, 64);
        if (lane < 32) sHid[lane] = fmaxf(s0r + mb1[o], 0.0f);
    }
    lds_fence();
    {
        float sA = mb2[lane], sB = mb2[64 + lane];
        #pragma unroll 8
        for (int q = 0; q < 32; ++q) {
            const float wA = mw2[q * 128 + lane];
            const float wB = mw2[q * 128 + 64 + lane];
            const float h0 = sHid[q];
            sA = fmaf(h0, wA, sA);  sB = fmaf(h0, wB, sB);
        }
        float rA = fmaxf(sA, 0.0f) + 1e-6f, rB = fmaxf(sB, 0.0f) + 1e-6f;
        float uA = rA, uB = rB;
        #pragma unroll
        for (int m = 1; m < 64; m <<= 1) {
            uA += __shfl_xor(uA, m, 64);  uB += __shfl_xor(uB, m, 64);
        }
        out[b * 64 + lane]        = rB / (uB + 1e-6f);
        out[OUT2 + b * 64 + lane] = 98.425f * rA / (uA + 1e-6f);
    }
}

extern "C" void kernel_launch(void* const* d_in, const int* in_sizes, int n_in,
                              void* d_out, int out_size, void* d_ws, size_t ws_size,
                              hipStream_t stream) {
    const float* users = (const float*)d_in[0];
    const float* W1    = (const float*)d_in[1];
    const float* a1    = (const float*)d_in[2];
    const float* W2    = (const float*)d_in[3];
    const float* a2    = (const float*)d_in[4];
    const float* mw1   = (const float*)d_in[5];
    const float* mb1   = (const float*)d_in[6];
    const float* mw2   = (const float*)d_in[7];
    const float* mb2   = (const float*)d_in[8];
    float* out = (float*)d_out;

    f16*   w2b  = (f16*)d_ws;
    float* w1a  = (float*)((char*)d_ws + 32768);
    f16*   w2ab = (f16*)((char*)d_ws + 32800);

    prep<<<64, 256, 0, stream>>>(W2, W1, a1, a2, w2b, w1a, w2ab);
    gat_kernel<<<NBATCH / 4, 256, 0, stream>>>(users, W1, w2b, w1a, w2ab,
                                               mw1, mb1, mw2, mb2, out);
}

// Round 10
// 113.064 us; speedup vs baseline: 1.0388x; 1.0388x over previous
//
#include <hip/hip_runtime.h>

#define NBATCH 4096
#define OUT2 (NBATCH * 64)

typedef _Float16 f16;
typedef __attribute__((ext_vector_type(8))) _Float16 f16x8;
typedef __attribute__((ext_vector_type(4))) float f32x4;

__device__ __forceinline__ float lrelu(float x) { return fmaxf(x, 0.2f * x); }
__device__ __forceinline__ float elu1(float x)  { return x > 0.0f ? x : __expf(x) - 1.0f; }
__device__ __forceinline__ void lds_fence() {
    asm volatile("s_waitcnt lgkmcnt(0)" ::: "memory");
}
// pack two f32 -> f16 (RNE, same as scalar casts) into one dword, low = a
__device__ __forceinline__ unsigned pk2(float a, float b) {
    union { f16 h[2]; unsigned u; } t;
    t.h[0] = (f16)a; t.h[1] = (f16)b;
    return t.u;
}
// 4-lane-group transpose: MFMA D-layout tile pair {t0,t1} -> A/B-frag.
// Target lane (c,q) elem j takes reg r=j&3 of tile (q>>1) from source lane
// (c, 2(q&1)+(j>>2)); s0 = c+32*(q&1), s1 = s0+16. Tile select AFTER the
// shuffle, in the destination lane (R6 bug: selecting before uses the source
// lane's predicate).
__device__ __forceinline__ f16x8 xpose(unsigned p0l, unsigned p0h,
                                       unsigned p1l, unsigned p1h,
                                       int s0, int s1, bool hiSel) {
    const unsigned a0l = (unsigned)__shfl((int)p0l, s0, 64);
    const unsigned a0h = (unsigned)__shfl((int)p0h, s0, 64);
    const unsigned b0l = (unsigned)__shfl((int)p0l, s1, 64);
    const unsigned b0h = (unsigned)__shfl((int)p0h, s1, 64);
    const unsigned a1l = (unsigned)__shfl((int)p1l, s0, 64);
    const unsigned a1h = (unsigned)__shfl((int)p1h, s0, 64);
    const unsigned b1l = (unsigned)__shfl((int)p1l, s1, 64);
    const unsigned b1h = (unsigned)__shfl((int)p1h, s1, 64);
    union { unsigned u[4]; f16x8 v; } o;
    o.u[0] = hiSel ? a1l : a0l;
    o.u[1] = hiSel ? a1h : a0h;
    o.u[2] = hiSel ? b1l : b0l;
    o.u[3] = hiSel ? b1h : b0h;
    return o.v;
}

// ---------------- prep ----------------
// ws: [0,32768)      w2b  f16 MFMA B-frags: w2b[((F2T*4+kf)*64+ln)*8+j] = W2[kf*32+(ln>>4)*8+j][F2T*16+(ln&15)]
//     [32768,32792)  w1a  f32[6] = {W1^T@a1[:128] (3), W1^T@a1[128:] (3)}
//     [32800,36896)  w2ab f16 B-frags of [W2@a2[:128] | W2@a2[128:]] (2 cols)
__global__ void prep(const float* __restrict__ W2, const float* __restrict__ W1,
                     const float* __restrict__ a1, const float* __restrict__ a2,
                     f16* __restrict__ w2b, float* __restrict__ w1a, f16* __restrict__ w2ab) {
    const int flat = blockIdx.x * 256 + threadIdx.x;   // 0..16383
    const int slot = flat >> 3, j = flat & 7;
    const int F2T = slot >> 8, kf = (slot >> 6) & 3, ln = slot & 63;
    const int lq = ln >> 4, lr = ln & 15;
    w2b[flat] = (f16)W2[(kf * 32 + lq * 8 + j) * 128 + F2T * 16 + lr];
    if (flat < 2048) {
        const int ks = flat >> 9, ln2 = (flat >> 3) & 63, jj = flat & 7;
        const int k = ks * 32 + ((ln2 >> 4) & 3) * 8 + jj;
        const int n = ln2 & 15;
        float v = 0.f;
        if (n < 2) {
            const float* av = a2 + n * 128;
            for (int f2 = 0; f2 < 128; ++f2) v = fmaf(W2[k * 128 + f2], av[f2], v);
        }
        w2ab[flat] = (f16)v;
    }
    if (flat >= 16381) {   // last 3 threads: w1a
        const int c = flat - 16381;
        float si = 0.f, sj = 0.f;
        for (int f = 0; f < 128; ++f) {
            const float w = W1[c * 128 + f];
            si = fmaf(w, a1[f], si);
            sj = fmaf(w, a1[128 + f], sj);
        }
        w1a[c] = si; w1a[3 + c] = sj;
    }
}

// FOUR independent batch-waves per 256-thread block; LDS-free compute core.
// TERMINAL STATE (R0-R9 session synthesis): batch throughput/CU is invariant
// at ~16 batches / 46us across ILP-2, 1/2/4-wave blocks, LDS and LDS-free
// cores, VALU diet, full unroll, prefetch, and stagger — with every pipe <50%
// busy (VALUBusy ~47% = 4 waves/SIMD x per-wave issue demand; MFMA 13%; DS
// ~25%). The limiter is exposed dependency-chain latency under a 4-context
// in-order scheduler, not a counter-visible pipe. R9 additionally proved
// CONVOYING IS BENEFICIAL (staggered starts lose L1 sharing of the weight
// streams: 46.5 -> 77us) and that small codegen perturbations are a lottery —
// hence this verbatim revert to the measured-best variant (R8: 46.5us kernel,
// 113.38us bench).
// (256,2): VGPR cap 256 — R1 showed forcing a low cap spills catastrophically.
__global__ __launch_bounds__(256, 2)
void gat_kernel(const float* __restrict__ users,
                const float* __restrict__ W1,
                const f16* __restrict__ w2b,
                const float* __restrict__ w1a,
                const f16* __restrict__ w2ab,
                const float* __restrict__ mw1,
                const float* __restrict__ mb1,
                const float* __restrict__ mw2,
                const float* __restrict__ mb2,
                float* __restrict__ out)
{
    const int wid  = threadIdx.x >> 6;            // wave in block = batch slot
    const int b    = blockIdx.x * 4 + wid;
    const int lane = threadIdx.x & 63;
    const int lr   = lane & 15;
    const int lq   = lane >> 4;
    const int s0   = (lane & 15) | ((lane & 16) << 1);   // c + 32*(q&1)
    const int s1   = s0 + 16;
    const bool hiSel = (lane & 32) != 0;                 // q>>1

    __shared__ __align__(16) char smem[4 * 1280];
    char*  sw    = smem + wid * 1280;             // wave-private slice
    float* sSi   = (float*)(sw);                  // [64]
    float* sSj   = (float*)(sw + 256);            // [64]
    float* sPool = (float*)(sw + 512);            // [128]
    float* sHid  = (float*)(sw + 1024);           // [32]

    const float* u = users + b * 192;

    // ---- scores layer 1: rank-3 exact fp32 ----
    {
        const float x = u[lane * 3], y = u[lane * 3 + 1], z = u[lane * 3 + 2];
        sSi[lane] = fmaf(x, w1a[0], fmaf(y, w1a[1], z * w1a[2]));
        sSj[lane] = fmaf(x, w1a[3], fmaf(y, w1a[4], z * w1a[5]));
    }
    lds_fence();

    // ---- softmax-1 (inv folded into frags) + product-1 -> PU^T B-frags ----
    f16x8 bfr[4];        // normalized PU^T as B-frags (16 VGPRs)
    {
        float sjv[16];
        *(float4*)&sjv[0]  = *(const float4*)&sSj[lq * 8];
        *(float4*)&sjv[4]  = *(const float4*)&sSj[lq * 8 + 4];
        *(float4*)&sjv[8]  = *(const float4*)&sSj[32 + lq * 8];
        *(float4*)&sjv[12] = *(const float4*)&sSj[32 + lq * 8 + 4];
        f16x8 ap[4][2];
        #pragma unroll
        for (int mt = 0; mt < 4; ++mt) {
            const float si = sSi[mt * 16 + lr];
            float pv[16];
            float lsum = 0.f;
            #pragma unroll
            for (int jj = 0; jj < 8; ++jj) {
                const float p0 = __expf(lrelu(si + sjv[jj]));
                const float p1 = __expf(lrelu(si + sjv[8 + jj]));
                pv[jj] = p0; pv[8 + jj] = p1;
                lsum += p0 + p1;
            }
            lsum += __shfl_xor(lsum, 16, 64);
            lsum += __shfl_xor(lsum, 32, 64);
            const float inv = 1.0f / lsum;
            #pragma unroll
            for (int jj = 0; jj < 8; ++jj) {
                ap[mt][0][jj] = (f16)(pv[jj] * inv);
                ap[mt][1][jj] = (f16)(pv[8 + jj] * inv);
            }
        }
        // product-1: PU^T = U^T @ P1n^T  (P already normalized)
        f16x8 af2[2];
        #pragma unroll
        for (int ks = 0; ks < 2; ++ks) {
            #pragma unroll
            for (int jj = 0; jj < 8; ++jj) {
                const int node = ks * 32 + lq * 8 + jj;
                af2[ks][jj] = (lr < 3) ? (f16)u[node * 3 + lr] : (f16)0.f;
            }
        }
        #pragma unroll
        for (int nt = 0; nt < 4; ++nt) {
            f32x4 d1 = (f32x4){0.f, 0.f, 0.f, 0.f};
            d1 = __builtin_amdgcn_mfma_f32_16x16x32_f16(af2[0], ap[nt][0], d1, 0, 0, 0);
            d1 = __builtin_amdgcn_mfma_f32_16x16x32_f16(af2[1], ap[nt][1], d1, 0, 0, 0);
            const float c0 = __shfl(d1[0], lr, 64);
            const float c1 = __shfl(d1[1], lr, 64);
            const float c2 = __shfl(d1[2], lr, 64);
            #pragma unroll
            for (int jj = 0; jj < 8; ++jj) bfr[nt][jj] = (f16)0.f;
            if (lq == 0) {
                bfr[nt][0] = (f16)c0; bfr[nt][1] = (f16)c1; bfr[nt][2] = (f16)c2;
            }
        }
    }

    // ===== layer-1: h1^T = W1^T @ PUn^T, in-register transpose to A-frags =====
    // Per (h, ksl): compute D-tiles ftl = {2ksl, 2ksl+1} for all nt (32 f32
    // live), then elu+pack+xpose -> hf[nt][2h+ksl]. No LDS, no fences.
    f16x8 hf[4][4];      // 64 VGPRs: h1 A-frags
    #pragma unroll
    for (int h = 0; h < 2; ++h) {
        #pragma unroll
        for (int ksl = 0; ksl < 2; ++ksl) {
            f32x4 acc[4][2];
            #pragma unroll
            for (int tp = 0; tp < 2; ++tp) {
                const int ftl = 2 * ksl + tp;
                f16x8 af3;      // W1^T A-frag
                #pragma unroll
                for (int jj = 0; jj < 8; ++jj) af3[jj] = (f16)0.f;
                if (lq == 0) {
                    #pragma unroll
                    for (int jj = 0; jj < 3; ++jj)
                        af3[jj] = (f16)W1[jj * 128 + (h * 4 + ftl) * 16 + lr];
                }
                #pragma unroll
                for (int nt = 0; nt < 4; ++nt) {
                    acc[nt][tp] = (f32x4){0.f, 0.f, 0.f, 0.f};
                    acc[nt][tp] = __builtin_amdgcn_mfma_f32_16x16x32_f16(af3, bfr[nt], acc[nt][tp], 0, 0, 0);
                }
            }
            #pragma unroll
            for (int nt = 0; nt < 4; ++nt) {
                const unsigned p0l = pk2(elu1(acc[nt][0][0]), elu1(acc[nt][0][1]));
                const unsigned p0h = pk2(elu1(acc[nt][0][2]), elu1(acc[nt][0][3]));
                const unsigned p1l = pk2(elu1(acc[nt][1][0]), elu1(acc[nt][1][1]));
                const unsigned p1h = pk2(elu1(acc[nt][1][2]), elu1(acc[nt][1][3]));
                hf[nt][h * 2 + ksl] = xpose(p0l, p0h, p1l, p1h, s0, s1, hiSel);
            }
        }
    }

    // ---- scores layer 2 via MFMA ----
    {
        f32x4 sacc[4];
        #pragma unroll
        for (int mt = 0; mt < 4; ++mt) sacc[mt] = (f32x4){0.f, 0.f, 0.f, 0.f};
        #pragma unroll
        for (int ks = 0; ks < 4; ++ks) {
            f16x8 bsw = *(const f16x8*)(w2ab + (ks * 64 + lane) * 8);
            #pragma unroll
            for (int mt = 0; mt < 4; ++mt)
                sacc[mt] = __builtin_amdgcn_mfma_f32_16x16x32_f16(hf[mt][ks], bsw, sacc[mt], 0, 0, 0);
        }
        lds_fence();   // softmax-1's sSi/sSj reads ordered before overwrite
        if (lr < 2) {
            float* dst = (lr == 0) ? sSi : sSj;
            #pragma unroll
            for (int mt = 0; mt < 4; ++mt)
                #pragma unroll
                for (int r = 0; r < 4; ++r)
                    dst[mt * 16 + lq * 4 + r] = sacc[mt][r];
        }
    }
    lds_fence();

    // ---- softmax-2 built once (inv2 folded into bp) ----
    f16x8 bp[4][2];      // 32 VGPRs
    {
        float sjv[16];
        *(float4*)&sjv[0]  = *(const float4*)&sSj[lq * 8];
        *(float4*)&sjv[4]  = *(const float4*)&sSj[lq * 8 + 4];
        *(float4*)&sjv[8]  = *(const float4*)&sSj[32 + lq * 8];
        *(float4*)&sjv[12] = *(const float4*)&sSj[32 + lq * 8 + 4];
        #pragma unroll
        for (int mt = 0; mt < 4; ++mt) {
            const float si = sSi[mt * 16 + lr];
            float pv[16];
            float lsum = 0.f;
            #pragma unroll
            for (int jj = 0; jj < 8; ++jj) {
                const float p0 = __expf(lrelu(si + sjv[jj]));
                const float p1 = __expf(lrelu(si + sjv[8 + jj]));
                pv[jj] = p0; pv[8 + jj] = p1;
                lsum += p0 + p1;
            }
            lsum += __shfl_xor(lsum, 16, 64);
            lsum += __shfl_xor(lsum, 32, 64);
            const float inv = 1.0f / lsum;
            #pragma unroll
            for (int jj = 0; jj < 8; ++jj) {
                bp[mt][0][jj] = (f16)(pv[jj] * inv);
                bp[mt][1][jj] = (f16)(pv[8 + jj] * inv);
            }
        }
    }

    // ======= fused F + E1, fully in-register, fully unrolled =======
    #pragma unroll
    for (int ft = 0; ft < 8; ++ft) {
        f16x8 bw2[4];
        #pragma unroll
        for (int kf = 0; kf < 4; ++kf)
            bw2[kf] = *(const f16x8*)(w2b + ((ft * 4 + kf) * 64 + lane) * 8);
        unsigned pkq[4][2];
        #pragma unroll
        for (int nt = 0; nt < 4; ++nt) {
            f32x4 acc = (f32x4){0.f, 0.f, 0.f, 0.f};
            #pragma unroll
            for (int kf = 0; kf < 4; ++kf)
                acc = __builtin_amdgcn_mfma_f32_16x16x32_f16(hf[nt][kf], bw2[kf], acc, 0, 0, 0);
            pkq[nt][0] = pk2(acc[0], acc[1]);
            pkq[nt][1] = pk2(acc[2], acc[3]);
        }
        const f16x8 bh0 = xpose(pkq[0][0], pkq[0][1], pkq[1][0], pkq[1][1], s0, s1, hiSel);
        const f16x8 bh1 = xpose(pkq[2][0], pkq[2][1], pkq[3][0], pkq[3][1], s0, s1, hiSel);

        float mx = -1e30f;
        #pragma unroll
        for (int mt = 0; mt < 4; ++mt) {
            f32x4 acc = (f32x4){0.f, 0.f, 0.f, 0.f};
            acc = __builtin_amdgcn_mfma_f32_16x16x32_f16(bp[mt][0], bh0, acc, 0, 0, 0);
            acc = __builtin_amdgcn_mfma_f32_16x16x32_f16(bp[mt][1], bh1, acc, 0, 0, 0);
            mx = fmaxf(mx, fmaxf(fmaxf(acc[0], acc[1]), fmaxf(acc[2], acc[3])));
        }
        mx = fmaxf(mx, __shfl_xor(mx, 16, 64));
        mx = fmaxf(mx, __shfl_xor(mx, 32, 64));
        if (lane < 16) sPool[ft * 16 + lane] = elu1(mx);
    }
    lds_fence();

    // ================= Readout =================
    {
        const int o = lane & 31, hh = lane >> 5;
        float s0r = 0.f;
        #pragma unroll 8
        for (int kk = 0; kk < 64; ++kk) {
            const int c = hh * 64 + kk;
            s0r = fmaf(sPool[c], mw1[c * 32 + o], s0r);
        }
        s0r += __shfl_xor(s0r, 32, 64);
        if (lane < 32) sHid[lane] = fmaxf(s0r + mb1[o], 0.0f);
    }
    lds_fence();
    {
        float sA = mb2[lane], sB = mb2[64 + lane];
        #pragma unroll 8
        for (int q = 0; q < 32; ++q) {
            const float wA = mw2[q * 128 + lane];
            const float wB = mw2[q * 128 + 64 + lane];
            const float h0 = sHid[q];
            sA = fmaf(h0, wA, sA);  sB = fmaf(h0, wB, sB);
        }
        float rA = fmaxf(sA, 0.0f) + 1e-6f, rB = fmaxf(sB, 0.0f) + 1e-6f;
        float uA = rA, uB = rB;
        #pragma unroll
        for (int m = 1; m < 64; m <<= 1) {
            uA += __shfl_xor(uA, m, 64);  uB += __shfl_xor(uB, m, 64);
        }
        out[b * 64 + lane]        = rB / (uB + 1e-6f);
        out[OUT2 + b * 64 + lane] = 98.425f * rA / (uA + 1e-6f);
    }
}

extern "C" void kernel_launch(void* const* d_in, const int* in_sizes, int n_in,
                              void* d_out, int out_size, void* d_ws, size_t ws_size,
                              hipStream_t stream) {
    const float* users = (const float*)d_in[0];
    const float* W1    = (const float*)d_in[1];
    const float* a1    = (const float*)d_in[2];
    const float* W2    = (const float*)d_in[3];
    const float* a2    = (const float*)d_in[4];
    const float* mw1   = (const float*)d_in[5];
    const float* mb1   = (const float*)d_in[6];
    const float* mw2   = (const float*)d_in[7];
    const float* mb2   = (const float*)d_in[8];
    float* out = (float*)d_out;

    f16*   w2b  = (f16*)d_ws;
    float* w1a  = (float*)((char*)d_ws + 32768);
    f16*   w2ab = (f16*)((char*)d_ws + 32800);

    prep<<<64, 256, 0, stream>>>(W2, W1, a1, a2, w2b, w1a, w2ab);
    gat_kernel<<<NBATCH / 4, 256, 0, stream>>>(users, W1, w2b, w1a, w2ab,
                                               mw1, mb1, mw2, mb2, out);
}